// Round 1
// 1342.281 us; speedup vs baseline: 1.5666x; 1.5666x over previous
//
#include <hip/hip_runtime.h>
#include <math.h>
#include <stdint.h>

// VectorQuantization, round 3: pre-split bf16 hi/lo to workspace, then pure
// bf16 MFMA GEMM (3-term) with fused argmax. Split work (the 41% VALUBusy in
// round 2) is hoisted into a one-shot memory-bound pre-pass; main kernel
// stages via global_load_lds(16B) and reads conflict-free ds_read_b128 frags.
//
// x: [B=16, D=512, N=8192] fp32, embed: [K=2048, D=512] fp32.
// out = quantize [B,D,N] fp32 ++ embed_ind [B,N] as fp32.
// MFMA floor: 3*2.75e11 FLOP / 2.5 PF = 330 us.

constexpr int B = 16, D = 512, N = 8192, K = 2048;

typedef __attribute__((ext_vector_type(8)))  short   short8;    // bf16x8 frag
typedef __attribute__((ext_vector_type(16))) float   floatx16;  // 32x32 acc

typedef const __attribute__((address_space(1))) uint32_t* gas1_t;
typedef __attribute__((address_space(3)))       uint32_t* las3_t;

__device__ __forceinline__ void async_ld16(const void* g, void* lds) {
  // 16B per lane, LDS dest = wave-uniform base + lane*16
  __builtin_amdgcn_global_load_lds((gas1_t)g, (las3_t)lds, 16, 0, 0);
}

__device__ __forceinline__ uint32_t rne_hi(float a) {
  uint32_t u = __float_as_uint(a);
  return (u + 0x7fffu + ((u >> 16) & 1u)) & 0xffff0000u;
}

// split pair (a,b) -> hi = packed(bf16(a), bf16(b)), lo = packed residuals
__device__ __forceinline__ void split2(float a, float b, uint32_t& hi, uint32_t& lo) {
  uint32_t ha = rne_hi(a), hb = rne_hi(b);
  float ra = a - __uint_as_float(ha);
  float rb = b - __uint_as_float(hb);
  hi = (ha >> 16) | hb;
  uint32_t la = rne_hi(ra), lb = rne_hi(rb);
  lo = (la >> 16) | lb;
}

// ---- kernel: e2[k] = sum_d embed[k][d]^2 ----
__global__ __launch_bounds__(256) void e2_kernel(const float* __restrict__ embed,
                                                 float* __restrict__ e2) {
  int k = blockIdx.x * 4 + (threadIdx.x >> 6);
  int lane = threadIdx.x & 63;
  const float* row = embed + (size_t)k * D;
  float s = 0.f;
  #pragma unroll
  for (int d = 0; d < D; d += 64) {
    float v = row[d + lane];
    s = fmaf(v, v, s);
  }
  #pragma unroll
  for (int off = 32; off; off >>= 1) s += __shfl_down(s, off, 64);
  if (lane == 0) e2[k] = s;
}

// ---- pre-pass: split x into bf16 hi/lo, packed [b][d/8][n][8] ----
// B-fragment order: 8 consecutive d per n = one 16B short8 per lane.
__global__ __launch_bounds__(256) void split_x(const float* __restrict__ x,
                                               ushort* __restrict__ xhi,
                                               ushort* __restrict__ xlo) {
  const int n = blockIdx.x * 256 + threadIdx.x;
  const int g = blockIdx.y;             // d-group (8 d's), 64 per b
  const int b = blockIdx.z;
  const float* src = x + (size_t)(b * 64 + g) * 8 * N + n;
  union { ushort u[8]; short8 s; } H, L;
  #pragma unroll
  for (int r = 0; r < 8; ++r) {
    float a = src[(size_t)r * N];       // coalesced across threads per row
    uint32_t ha = rne_hi(a);
    float ra = a - __uint_as_float(ha);
    uint32_t la = rne_hi(ra);
    H.u[r] = (ushort)(ha >> 16);
    L.u[r] = (ushort)(la >> 16);
  }
  size_t o = ((size_t)(b * 64 + g) * N + n) * 8;
  *(short8*)&xhi[o] = H.s;              // 16B contiguous, coalesced
  *(short8*)&xlo[o] = L.s;
}

// ---- pre-pass: split embed into bf16 hi/lo in per-tile LDS order ----
// Tile (kt,dt) = 128 codes x 64 d, laid out [run=8][c=128][8] so the A-frag
// ds_read_b128 (lanes = consecutive c) is bank-conflict-free.
__global__ __launch_bounds__(256) void split_e(const float* __restrict__ embed,
                                               ushort* __restrict__ ehi,
                                               ushort* __restrict__ elo) {
  const int kt = blockIdx.x, dt = blockIdx.y;
  const int t = threadIdx.x;
  const int f4 = t & 15;                // 16 float4 per row = 64 d
  const int cr = t >> 4;                // 16 codes per pass
  const int run = f4 >> 1, half = f4 & 1;
  const size_t tileo = (size_t)(kt * 8 + dt) * 8192;  // 128*64 shorts per tile
  const float* eb = embed + (size_t)(kt * 128) * D + dt * 64;
  #pragma unroll
  for (int p = 0; p < 8; ++p) {
    int c = p * 16 + cr;
    const float4 v = *(const float4*)(eb + (size_t)c * D + f4 * 4);
    uint32_t h0, l0, h1, l1;
    split2(v.x, v.y, h0, l0);
    split2(v.z, v.w, h1, l1);
    size_t off = tileo + (size_t)(run * 128 + c) * 8 + half * 4;
    *(uint2*)&ehi[off] = make_uint2(h0, h1);
    *(uint2*)&elo[off] = make_uint2(l0, l1);
  }
}

// ---- main kernel: 128 n-rows x 128-code tiles, pure bf16 MFMA ----
__global__ __launch_bounds__(256, 2) void vq_mfma2(const ushort* __restrict__ xhi,
                                                   const ushort* __restrict__ xlo,
                                                   const ushort* __restrict__ ehi,
                                                   const ushort* __restrict__ elo,
                                                   const float* __restrict__ e2g,
                                                   const float* __restrict__ embed,
                                                   float* __restrict__ out) {
  // LDS: 64 KB tiles + 4.5 KB reduction = 70 KB -> 2 blocks/CU
  __shared__ ushort Xh[8192], Xl[8192];   // [run=8][n=128][8] bf16 (16 KB each)
  __shared__ ushort Eh[8192], El[8192];   // [run=8][c=128][8] bf16 (16 KB each)
  __shared__ float redV[512];
  __shared__ int   redI[512];
  __shared__ int   fIdx[128];

  const int t    = threadIdx.x;
  const int lane = t & 63;
  const int wid  = t >> 6;
  const int wm   = wid & 1;    // code-dim wave coord
  const int wn   = wid >> 1;   // n-dim wave coord
  const int l31  = lane & 31;
  const int lh   = lane >> 5;  // half-wave

  const int b  = blockIdx.y;
  const int n0 = blockIdx.x * 128;

  float bestV[2] = {-3.402823466e38f, -3.402823466e38f};
  int   bestI[2] = {0, 0};

  for (int kt = 0; kt < K / 128; ++kt) {
    floatx16 acc[2][2];
    #pragma unroll
    for (int mt = 0; mt < 2; ++mt)
      #pragma unroll
      for (int nt = 0; nt < 2; ++nt)
        #pragma unroll
        for (int i = 0; i < 16; ++i) acc[mt][nt][i] = 0.f;

    for (int dt = 0; dt < D / 64; ++dt) {
      // ---- stage X: async bf16, wave wid loads groups wid*2, wid*2+1 ----
      #pragma unroll
      for (int i = 0; i < 2; ++i) {
        int gg = wid * 2 + i;
        const ushort* sh = xhi + ((size_t)(b * 64 + dt * 8 + gg) * N + n0) * 8;
        const ushort* sl = xlo + ((size_t)(b * 64 + dt * 8 + gg) * N + n0) * 8;
        #pragma unroll
        for (int j = 0; j < 2; ++j) {
          async_ld16(sh + (size_t)j * 512 + lane * 8, &Xh[gg * 1024 + j * 512]);
          async_ld16(sl + (size_t)j * 512 + lane * 8, &Xl[gg * 1024 + j * 512]);
        }
      }
      // ---- stage E: contiguous pre-swizzled tile, 4 KB per wave ----
      {
        const size_t tileo = (size_t)(kt * 8 + dt) * 8192;
        const ushort* sh = ehi + tileo + wid * 2048;
        const ushort* sl = elo + tileo + wid * 2048;
        #pragma unroll
        for (int i = 0; i < 4; ++i) {
          async_ld16(sh + i * 512 + lane * 8, &Eh[wid * 2048 + i * 512]);
          async_ld16(sl + i * 512 + lane * 8, &El[wid * 2048 + i * 512]);
        }
      }
      __syncthreads();   // compiler drains vmcnt(0) for global_load_lds here

      #pragma unroll
      for (int ks = 0; ks < 4; ++ks) {
        const int run = ks * 2 + lh;
        // A fragments (embed): m = l31 within 32-code block
        short8 ah[2], al[2];
        #pragma unroll
        for (int mt = 0; mt < 2; ++mt) {
          int c = wm * 64 + mt * 32 + l31;
          int eo = (run * 128 + c) * 8;
          ah[mt] = *(const short8*)&Eh[eo];
          al[mt] = *(const short8*)&El[eo];
        }
        // B fragments (x): n = l31 within 32-n block
        short8 bh[2], bl[2];
        #pragma unroll
        for (int nt = 0; nt < 2; ++nt) {
          int n = wn * 64 + nt * 32 + l31;
          int xo = (run * 128 + n) * 8;
          bh[nt] = *(const short8*)&Xh[xo];
          bl[nt] = *(const short8*)&Xl[xo];
        }
        #pragma unroll
        for (int mt = 0; mt < 2; ++mt)
          #pragma unroll
          for (int nt = 0; nt < 2; ++nt) {
            acc[mt][nt] = __builtin_amdgcn_mfma_f32_32x32x16_bf16(
                ah[mt], bh[nt], acc[mt][nt], 0, 0, 0);
            acc[mt][nt] = __builtin_amdgcn_mfma_f32_32x32x16_bf16(
                ah[mt], bl[nt], acc[mt][nt], 0, 0, 0);
            acc[mt][nt] = __builtin_amdgcn_mfma_f32_32x32x16_bf16(
                al[mt], bh[nt], acc[mt][nt], 0, 0, 0);
          }
      }
      __syncthreads();
    } // dt

    // ---- fold into running argmax (ascending code order -> first-max) ----
    #pragma unroll
    for (int mt = 0; mt < 2; ++mt) {
      #pragma unroll
      for (int r = 0; r < 16; ++r) {
        int row  = (r & 3) + 8 * (r >> 2) + 4 * lh;
        int code = kt * 128 + wm * 64 + mt * 32 + row;
        float ek = e2g[code];
        #pragma unroll
        for (int nt = 0; nt < 2; ++nt) {
          float s = 2.0f * acc[mt][nt][r] - ek;
          if (s > bestV[nt]) { bestV[nt] = s; bestI[nt] = code; }
        }
      }
    }
  } // kt

  // ---- cross-wave reduction ----
  __syncthreads();
  #pragma unroll
  for (int nt = 0; nt < 2; ++nt) {
    int n = wn * 64 + nt * 32 + l31;
    int slot = lh + 2 * wm;
    redV[n * 4 + slot] = bestV[nt];
    redI[n * 4 + slot] = bestI[nt];
  }
  __syncthreads();
  if (t < 128) {
    float bv = redV[t * 4]; int bi = redI[t * 4];
    #pragma unroll
    for (int s = 1; s < 4; ++s) {
      float v = redV[t * 4 + s]; int ii = redI[t * 4 + s];
      if (v > bv || (v == bv && ii < bi)) { bv = v; bi = ii; }
    }
    fIdx[t] = bi;
    out[(size_t)B * D * N + (size_t)b * N + n0 + t] = (float)bi;
  }
  __syncthreads();

  // ---- fused gather: out[b][d][n0+n] = embed[fIdx[n]][d] ----
  {
    int n = t & 127;
    int code = fIdx[n];
    const float* erow = embed + (size_t)code * D;
    float* ob = out + (size_t)b * D * N + n0 + n;
    for (int d = (t >> 7); d < D; d += 2) {
      ob[(size_t)d * N] = erow[d];
    }
  }
}

// ===================== fallback path (round-2 kernel) =====================
__global__ __launch_bounds__(256, 2) void vq_mfma(const float* __restrict__ x,
                                                  const float* __restrict__ embed,
                                                  const float* __restrict__ e2g,
                                                  float* __restrict__ out) {
  __shared__ float    Xraw[64 * 128];
  __shared__ uint16_t Ehi[128 * 64];
  __shared__ uint16_t Elo[128 * 64];

  const int t    = threadIdx.x;
  const int lane = t & 63;
  const int wid  = t >> 6;
  const int wm   = wid & 1;
  const int wn   = wid >> 1;
  const int l31  = lane & 31;
  const int lh   = lane >> 5;

  const int b  = blockIdx.y;
  const int n0 = blockIdx.x * 128;
  const float* xb = x + (size_t)b * D * N + n0;

  float bestV[2] = {-3.402823466e38f, -3.402823466e38f};
  int   bestI[2] = {0, 0};

  for (int kt = 0; kt < K / 128; ++kt) {
    floatx16 acc[2][2];
    #pragma unroll
    for (int mt = 0; mt < 2; ++mt)
      #pragma unroll
      for (int nt = 0; nt < 2; ++nt)
        #pragma unroll
        for (int i = 0; i < 16; ++i) acc[mt][nt][i] = 0.f;

    for (int dt = 0; dt < D / 64; ++dt) {
      {
        const float* g0 = xb + (size_t)(dt * 64 + wid * 16 + lh) * N + l31 * 4;
        #pragma unroll
        for (int i = 0; i < 8; ++i) {
          async_ld16(g0 + (size_t)(i * 2) * N, &Xraw[(wid * 16 + i * 2) * 128]);
        }
      }
      {
        const float* eb = embed + (size_t)(kt * 128) * D + dt * 64;
        const int f4 = t & 15;
        const int cr = t >> 4;
        #pragma unroll
        for (int p = 0; p < 8; ++p) {
          int c = p * 16 + cr;
          const float4 v = *(const float4*)(eb + (size_t)c * D + f4 * 4);
          uint32_t h0, l0, h1, l1;
          split2(v.x, v.y, h0, l0);
          split2(v.z, v.w, h1, l1);
          int run = f4 >> 1, half = f4 & 1;
          int off = ((run ^ (c & 7)) * 8 + half * 4);
          *(uint2*)&Ehi[c * 64 + off] = make_uint2(h0, h1);
          *(uint2*)&Elo[c * 64 + off] = make_uint2(l0, l1);
        }
      }
      __syncthreads();

      #pragma unroll
      for (int ks = 0; ks < 4; ++ks) {
        short8 ahi[2], alo[2];
        #pragma unroll
        for (int mt = 0; mt < 2; ++mt) {
          int c = wm * 64 + mt * 32 + l31;
          int run = ks * 2 + lh;
          int off = (run ^ (c & 7)) * 8;
          ahi[mt] = *(const short8*)&Ehi[c * 64 + off];
          alo[mt] = *(const short8*)&Elo[c * 64 + off];
        }
        short8 bhi[2], blo[2];
        #pragma unroll
        for (int nt = 0; nt < 2; ++nt) {
          int n = wn * 64 + nt * 32 + l31;
          int kb = ks * 16 + lh * 8;
          float r0 = Xraw[(kb + 0) * 128 + n];
          float r1 = Xraw[(kb + 1) * 128 + n];
          float r2 = Xraw[(kb + 2) * 128 + n];
          float r3 = Xraw[(kb + 3) * 128 + n];
          float r4 = Xraw[(kb + 4) * 128 + n];
          float r5 = Xraw[(kb + 5) * 128 + n];
          float r6 = Xraw[(kb + 6) * 128 + n];
          float r7 = Xraw[(kb + 7) * 128 + n];
          union { short8 s; uint32_t u[4]; } Bh, Bl;
          split2(r0, r1, Bh.u[0], Bl.u[0]);
          split2(r2, r3, Bh.u[1], Bl.u[1]);
          split2(r4, r5, Bh.u[2], Bl.u[2]);
          split2(r6, r7, Bh.u[3], Bl.u[3]);
          bhi[nt] = Bh.s; blo[nt] = Bl.s;
        }
        #pragma unroll
        for (int mt = 0; mt < 2; ++mt)
          #pragma unroll
          for (int nt = 0; nt < 2; ++nt) {
            acc[mt][nt] = __builtin_amdgcn_mfma_f32_32x32x16_bf16(
                ahi[mt], bhi[nt], acc[mt][nt], 0, 0, 0);
            acc[mt][nt] = __builtin_amdgcn_mfma_f32_32x32x16_bf16(
                ahi[mt], blo[nt], acc[mt][nt], 0, 0, 0);
            acc[mt][nt] = __builtin_amdgcn_mfma_f32_32x32x16_bf16(
                alo[mt], bhi[nt], acc[mt][nt], 0, 0, 0);
          }
      }
      __syncthreads();
    } // dt

    #pragma unroll
    for (int mt = 0; mt < 2; ++mt) {
      #pragma unroll
      for (int r = 0; r < 16; ++r) {
        int row  = (r & 3) + 8 * (r >> 2) + 4 * lh;
        int code = kt * 128 + wm * 64 + mt * 32 + row;
        float ek = e2g[code];
        #pragma unroll
        for (int nt = 0; nt < 2; ++nt) {
          float s = 2.0f * acc[mt][nt][r] - ek;
          if (s > bestV[nt]) { bestV[nt] = s; bestI[nt] = code; }
        }
      }
    }
  } // kt

  __syncthreads();
  float* redV = Xraw;
  int*   redI = (int*)(Xraw + 512);
  int*   fIdx = (int*)(Xraw + 1024);

  #pragma unroll
  for (int nt = 0; nt < 2; ++nt) {
    int n = wn * 64 + nt * 32 + l31;
    int slot = lh + 2 * wm;
    redV[n * 4 + slot] = bestV[nt];
    redI[n * 4 + slot] = bestI[nt];
  }
  __syncthreads();
  if (t < 128) {
    float bv = redV[t * 4]; int bi = redI[t * 4];
    #pragma unroll
    for (int s = 1; s < 4; ++s) {
      float v = redV[t * 4 + s]; int ii = redI[t * 4 + s];
      if (v > bv || (v == bv && ii < bi)) { bv = v; bi = ii; }
    }
    fIdx[t] = bi;
    out[(size_t)B * D * N + (size_t)b * N + n0 + t] = (float)bi;
  }
  __syncthreads();

  {
    int n = t & 127;
    int code = fIdx[n];
    const float* erow = embed + (size_t)code * D;
    float* ob = out + (size_t)b * D * N + n0 + n;
    for (int d = (t >> 7); d < D; d += 2) {
      ob[(size_t)d * N] = erow[d];
    }
  }
}

extern "C" void kernel_launch(void* const* d_in, const int* in_sizes, int n_in,
                              void* d_out, int out_size, void* d_ws, size_t ws_size,
                              hipStream_t stream) {
  const float* x     = (const float*)d_in[0];
  const float* embed = (const float*)d_in[1];
  float* out = (float*)d_out;

  const size_t ES = (size_t)K * D;          // shorts per embed plane
  const size_t XS = (size_t)B * D * N;      // shorts per x plane
  const size_t need = 8192 + 2 * ES * 2 + 2 * XS * 2;  // 272,637,952 B

  float* e2 = (float*)d_ws;                 // 2048 floats (8 KB)

  if (ws_size >= need) {
    ushort* eh = (ushort*)((char*)d_ws + 8192);
    ushort* el = eh + ES;
    ushort* xh = el + ES;
    ushort* xl = xh + XS;
    e2_kernel<<<dim3(K / 4), 256, 0, stream>>>(embed, e2);
    split_e<<<dim3(K / 128, D / 64), 256, 0, stream>>>(embed, eh, el);
    split_x<<<dim3(N / 256, D / 8, B), 256, 0, stream>>>(x, xh, xl);
    vq_mfma2<<<dim3(N / 128, B), 256, 0, stream>>>(xh, xl, eh, el, e2, embed, out);
  } else {
    e2_kernel<<<dim3(K / 4), 256, 0, stream>>>(embed, e2);
    vq_mfma<<<dim3(N / 128, B), 256, 0, stream>>>(x, embed, e2, out);
  }
}

// Round 2
// 1284.736 us; speedup vs baseline: 1.6368x; 1.0448x over previous
//
#include <hip/hip_runtime.h>
#include <math.h>
#include <stdint.h>

// VectorQuantization, round 4: staged-bytes cut (256c x 256n tile, 8 kt trips)
// + 2-phase double-buffered pipeline (T3-min) + mt=4/nt=2 wave tile.
// x: [B=16, D=512, N=8192] fp32, embed: [K=2048, D=512] fp32.
// out = quantize [B,D,N] fp32 ++ embed_ind [B,N] as fp32.
// MFMA floor: 3*2.75e11 FLOP / 2.5 PF = 330 us.

constexpr int B = 16, D = 512, N = 8192, K = 2048;

typedef __attribute__((ext_vector_type(8)))  short   short8;    // bf16x8 frag
typedef __attribute__((ext_vector_type(16))) float   floatx16;  // 32x32 acc

typedef const __attribute__((address_space(1))) uint32_t* gas1_t;
typedef __attribute__((address_space(3)))       uint32_t* las3_t;

__device__ __forceinline__ void async_ld16(const void* g, void* lds) {
  // 16B per lane, LDS dest = wave-uniform base + lane*16
  __builtin_amdgcn_global_load_lds((gas1_t)g, (las3_t)lds, 16, 0, 0);
}

__device__ __forceinline__ uint32_t rne_hi(float a) {
  uint32_t u = __float_as_uint(a);
  return (u + 0x7fffu + ((u >> 16) & 1u)) & 0xffff0000u;
}

// split pair (a,b) -> hi = packed(bf16(a), bf16(b)), lo = packed residuals
__device__ __forceinline__ void split2(float a, float b, uint32_t& hi, uint32_t& lo) {
  uint32_t ha = rne_hi(a), hb = rne_hi(b);
  float ra = a - __uint_as_float(ha);
  float rb = b - __uint_as_float(hb);
  hi = (ha >> 16) | hb;
  uint32_t la = rne_hi(ra), lb = rne_hi(rb);
  lo = (la >> 16) | lb;
}

// ---- kernel: e2[k] = sum_d embed[k][d]^2 ----
__global__ __launch_bounds__(256) void e2_kernel(const float* __restrict__ embed,
                                                 float* __restrict__ e2) {
  int k = blockIdx.x * 4 + (threadIdx.x >> 6);
  int lane = threadIdx.x & 63;
  const float* row = embed + (size_t)k * D;
  float s = 0.f;
  #pragma unroll
  for (int d = 0; d < D; d += 64) {
    float v = row[d + lane];
    s = fmaf(v, v, s);
  }
  #pragma unroll
  for (int off = 32; off; off >>= 1) s += __shfl_down(s, off, 64);
  if (lane == 0) e2[k] = s;
}

// ---- pre-pass: split x into bf16 hi/lo, per-step LDS-image layout ----
// Plane layout: [(b*32 + n/256)*16 + d/32] tiles of 8192 shorts,
// tile = [run=(d>>3)&3][n&255][d&7].
__global__ __launch_bounds__(256) void split_x(const float* __restrict__ x,
                                               ushort* __restrict__ xh,
                                               ushort* __restrict__ xl) {
  const int t  = threadIdx.x;
  const int n0 = blockIdx.x * 1024 + t * 4;
  const int g  = blockIdx.y;            // d-group of 8 (0..63)
  const int b  = blockIdx.z;
  const float* src = x + ((size_t)b * D + g * 8) * N + n0;
  union { ushort u[8]; short8 s; } H[4], L[4];
  #pragma unroll
  for (int r = 0; r < 8; ++r) {
    const float4 v = *(const float4*)(src + (size_t)r * N);  // 16B/lane coalesced
    const float a0 = v.x, a1 = v.y, a2 = v.z, a3 = v.w;
    uint32_t h; float res;
    h = rne_hi(a0); res = a0 - __uint_as_float(h); H[0].u[r] = (ushort)(h >> 16); L[0].u[r] = (ushort)(rne_hi(res) >> 16);
    h = rne_hi(a1); res = a1 - __uint_as_float(h); H[1].u[r] = (ushort)(h >> 16); L[1].u[r] = (ushort)(rne_hi(res) >> 16);
    h = rne_hi(a2); res = a2 - __uint_as_float(h); H[2].u[r] = (ushort)(h >> 16); L[2].u[r] = (ushort)(rne_hi(res) >> 16);
    h = rne_hi(a3); res = a3 - __uint_as_float(h); H[3].u[r] = (ushort)(h >> 16); L[3].u[r] = (ushort)(rne_hi(res) >> 16);
  }
  const size_t base = ((size_t)(b * 32 + (n0 >> 8)) * 16 + (g >> 2)) * 8192
                    + ((size_t)(g & 3) * 256 + (n0 & 255)) * 8;
  #pragma unroll
  for (int j = 0; j < 4; ++j) {         // 64B contiguous per lane, coalesced
    *(short8*)&xh[base + j * 8] = H[j].s;
    *(short8*)&xl[base + j * 8] = L[j].s;
  }
}

// ---- pre-pass: split embed, tiles [(c/256)*16 + d/32] of [run][c&255][d&7] ----
__global__ __launch_bounds__(256) void split_e(const float* __restrict__ embed,
                                               ushort* __restrict__ eh,
                                               ushort* __restrict__ el) {
  const int t = threadIdx.x;
  const int c = blockIdx.x * 16 + (t >> 4);
  const int kt2 = c >> 8, cl = c & 255;
  #pragma unroll
  for (int p = 0; p < 8; ++p) {
    int d0 = p * 64 + (t & 15) * 4;
    const float4 v = *(const float4*)(embed + (size_t)c * D + d0);
    uint32_t h0, l0, h1, l1;
    split2(v.x, v.y, h0, l0);
    split2(v.z, v.w, h1, l1);
    int dt2 = d0 >> 5, run = (d0 >> 3) & 3, e = d0 & 7;   // e in {0,4}
    size_t off = (size_t)(kt2 * 16 + dt2) * 8192 + ((size_t)run * 256 + cl) * 8 + e;
    *(uint2*)&eh[off] = make_uint2(h0, h1);
    *(uint2*)&el[off] = make_uint2(l0, l1);
  }
}

// ---- main kernel: 256 codes x 256 n per block, 2-phase dbuf pipeline ----
__global__ __launch_bounds__(512, 2) void vq_mfma3(const ushort* __restrict__ xh,
                                                   const ushort* __restrict__ xl,
                                                   const ushort* __restrict__ eh,
                                                   const ushort* __restrict__ el,
                                                   const float* __restrict__ e2g,
                                                   const float* __restrict__ embed,
                                                   float* __restrict__ out) {
  // LDS: 4 planes x dbuf x 16KB = 128 KB + 9.25 KB reduction = 137.25 KB -> 1 blk/CU
  __shared__ ushort Xh[2][8192], Xl[2][8192];   // [buf][run4][n256][8]
  __shared__ ushort Eh[2][8192], El[2][8192];   // [buf][run4][c256][8]
  __shared__ float redV[1024];
  __shared__ int   redI[1024];
  __shared__ int   fIdx[256];

  const int t    = threadIdx.x;
  const int lane = t & 63;
  const int wid  = t >> 6;     // 0..7
  const int wm   = wid & 1;    // code-dim wave coord (2 x 128 codes)
  const int wn   = wid >> 1;   // n-dim wave coord (4 x 64 n)
  const int l31  = lane & 31;
  const int lh   = lane >> 5;  // half-wave

  const int b  = blockIdx.y;
  const int nb = blockIdx.x;
  const int n0 = nb * 256;

  const size_t xbase = (size_t)(b * 32 + nb) * 16 * 8192;  // shorts

  float bestV[2] = {-3.402823466e38f, -3.402823466e38f};
  int   bestI[2] = {0, 0};

  floatx16 acc[4][2];
  #pragma unroll
  for (int mt = 0; mt < 4; ++mt)
    #pragma unroll
    for (int nt = 0; nt < 2; ++nt)
      #pragma unroll
      for (int i = 0; i < 16; ++i) acc[mt][nt][i] = 0.f;

  // stage step s (kt2 = s>>4, dt2 = s&15) into buffer `buf`: 64 KB, 8 instr/wave
  auto STAGE = [&](int s, int buf) {
    const int kt2 = s >> 4, dt2 = s & 15;
    const size_t xo = xbase + (size_t)dt2 * 8192;
    const size_t eo = (size_t)(kt2 * 16 + dt2) * 8192;
    #pragma unroll
    for (int i = 0; i < 2; ++i) {
      const int o = (wid * 2 + i) * 512;   // shorts; 1 KB per instruction
      async_ld16(xh + xo + o + lane * 8, &Xh[buf][o]);
      async_ld16(xl + xo + o + lane * 8, &Xl[buf][o]);
      async_ld16(eh + eo + o + lane * 8, &Eh[buf][o]);
      async_ld16(el + eo + o + lane * 8, &El[buf][o]);
    }
  };

  STAGE(0, 0);
  __syncthreads();   // drain prologue loads

  int cur = 0;
  for (int s = 0; s < 128; ++s) {
    if (s < 127) STAGE(s + 1, cur ^ 1);   // prefetch next step during compute

    #pragma unroll
    for (int ks = 0; ks < 2; ++ks) {
      const int run = ks * 2 + lh;
      short8 ah[4], al[4];
      #pragma unroll
      for (int mt = 0; mt < 4; ++mt) {
        const int eoff = (run * 256 + (wm * 128 + mt * 32 + l31)) * 8;
        ah[mt] = *(const short8*)&Eh[cur][eoff];
        al[mt] = *(const short8*)&El[cur][eoff];
      }
      short8 bh[2], bl[2];
      #pragma unroll
      for (int nt = 0; nt < 2; ++nt) {
        const int xoff = (run * 256 + (wn * 64 + nt * 32 + l31)) * 8;
        bh[nt] = *(const short8*)&Xh[cur][xoff];
        bl[nt] = *(const short8*)&Xl[cur][xoff];
      }
      #pragma unroll
      for (int mt = 0; mt < 4; ++mt)
        #pragma unroll
        for (int nt = 0; nt < 2; ++nt) {
          acc[mt][nt] = __builtin_amdgcn_mfma_f32_32x32x16_bf16(
              ah[mt], bh[nt], acc[mt][nt], 0, 0, 0);
          acc[mt][nt] = __builtin_amdgcn_mfma_f32_32x32x16_bf16(
              ah[mt], bl[nt], acc[mt][nt], 0, 0, 0);
          acc[mt][nt] = __builtin_amdgcn_mfma_f32_32x32x16_bf16(
              al[mt], bh[nt], acc[mt][nt], 0, 0, 0);
        }
    }

    if ((s & 15) == 15) {   // end of a 256-code tile: fold argmax, reset acc
      const int kt2 = s >> 4;
      #pragma unroll
      for (int mt = 0; mt < 4; ++mt) {
        #pragma unroll
        for (int r = 0; r < 16; ++r) {
          const int row  = (r & 3) + 8 * (r >> 2) + 4 * lh;
          const int code = kt2 * 256 + wm * 128 + mt * 32 + row;
          const float ek = e2g[code];
          #pragma unroll
          for (int nt = 0; nt < 2; ++nt) {
            const float sv = 2.0f * acc[mt][nt][r] - ek;
            if (sv > bestV[nt]) { bestV[nt] = sv; bestI[nt] = code; }
            acc[mt][nt][r] = 0.f;
          }
        }
      }
    }

    __syncthreads();   // drains vmcnt for prefetched loads; protects dbuf swap
    cur ^= 1;
  }

  // ---- cross-wave reduction: 4 candidates per n (lh x wm) ----
  #pragma unroll
  for (int nt = 0; nt < 2; ++nt) {
    const int n = wn * 64 + nt * 32 + l31;
    const int slot = lh * 2 + wm;
    redV[n * 4 + slot] = bestV[nt];
    redI[n * 4 + slot] = bestI[nt];
  }
  __syncthreads();
  if (t < 256) {
    float bv = redV[t * 4]; int bi = redI[t * 4];
    #pragma unroll
    for (int s = 1; s < 4; ++s) {
      float v = redV[t * 4 + s]; int ii = redI[t * 4 + s];
      if (v > bv || (v == bv && ii < bi)) { bv = v; bi = ii; }
    }
    fIdx[t] = bi;
    out[(size_t)B * D * N + (size_t)b * N + n0 + t] = (float)bi;
  }
  __syncthreads();

  // ---- fused gather: out[b][d][n0+n] = embed[fIdx[n]][d] ----
  {
    const int n = t & 255;
    const int code = fIdx[n];
    const float* erow = embed + (size_t)code * D;
    float* ob = out + (size_t)b * D * N + n0 + n;
    for (int d = (t >> 8); d < D; d += 2) {
      ob[(size_t)d * N] = erow[d];
    }
  }
}

// ===================== fallback path (round-2 kernel, small ws) =====================
__global__ __launch_bounds__(256, 2) void vq_mfma(const float* __restrict__ x,
                                                  const float* __restrict__ embed,
                                                  const float* __restrict__ e2g,
                                                  float* __restrict__ out) {
  __shared__ float    Xraw[64 * 128];
  __shared__ uint16_t Ehi[128 * 64];
  __shared__ uint16_t Elo[128 * 64];

  const int t    = threadIdx.x;
  const int lane = t & 63;
  const int wid  = t >> 6;
  const int wm   = wid & 1;
  const int wn   = wid >> 1;
  const int l31  = lane & 31;
  const int lh   = lane >> 5;

  const int b  = blockIdx.y;
  const int n0 = blockIdx.x * 128;
  const float* xb = x + (size_t)b * D * N + n0;

  float bestV[2] = {-3.402823466e38f, -3.402823466e38f};
  int   bestI[2] = {0, 0};

  for (int kt = 0; kt < K / 128; ++kt) {
    floatx16 acc[2][2];
    #pragma unroll
    for (int mt = 0; mt < 2; ++mt)
      #pragma unroll
      for (int nt = 0; nt < 2; ++nt)
        #pragma unroll
        for (int i = 0; i < 16; ++i) acc[mt][nt][i] = 0.f;

    for (int dt = 0; dt < D / 64; ++dt) {
      {
        const float* g0 = xb + (size_t)(dt * 64 + wid * 16 + lh) * N + l31 * 4;
        #pragma unroll
        for (int i = 0; i < 8; ++i) {
          async_ld16(g0 + (size_t)(i * 2) * N, &Xraw[(wid * 16 + i * 2) * 128]);
        }
      }
      {
        const float* eb = embed + (size_t)(kt * 128) * D + dt * 64;
        const int f4 = t & 15;
        const int cr = t >> 4;
        #pragma unroll
        for (int p = 0; p < 8; ++p) {
          int c = p * 16 + cr;
          const float4 v = *(const float4*)(eb + (size_t)c * D + f4 * 4);
          uint32_t h0, l0, h1, l1;
          split2(v.x, v.y, h0, l0);
          split2(v.z, v.w, h1, l1);
          int run = f4 >> 1, half = f4 & 1;
          int off = ((run ^ (c & 7)) * 8 + half * 4);
          *(uint2*)&Ehi[c * 64 + off] = make_uint2(h0, h1);
          *(uint2*)&Elo[c * 64 + off] = make_uint2(l0, l1);
        }
      }
      __syncthreads();

      #pragma unroll
      for (int ks = 0; ks < 4; ++ks) {
        short8 ahi[2], alo[2];
        #pragma unroll
        for (int mt = 0; mt < 2; ++mt) {
          int c = wm * 64 + mt * 32 + l31;
          int run = ks * 2 + lh;
          int off = (run ^ (c & 7)) * 8;
          ahi[mt] = *(const short8*)&Ehi[c * 64 + off];
          alo[mt] = *(const short8*)&Elo[c * 64 + off];
        }
        short8 bhi[2], blo[2];
        #pragma unroll
        for (int nt = 0; nt < 2; ++nt) {
          int n = wn * 64 + nt * 32 + l31;
          int kb = ks * 16 + lh * 8;
          float r0 = Xraw[(kb + 0) * 128 + n];
          float r1 = Xraw[(kb + 1) * 128 + n];
          float r2 = Xraw[(kb + 2) * 128 + n];
          float r3 = Xraw[(kb + 3) * 128 + n];
          float r4 = Xraw[(kb + 4) * 128 + n];
          float r5 = Xraw[(kb + 5) * 128 + n];
          float r6 = Xraw[(kb + 6) * 128 + n];
          float r7 = Xraw[(kb + 7) * 128 + n];
          union { short8 s; uint32_t u[4]; } Bh, Bl;
          split2(r0, r1, Bh.u[0], Bl.u[0]);
          split2(r2, r3, Bh.u[1], Bl.u[1]);
          split2(r4, r5, Bh.u[2], Bl.u[2]);
          split2(r6, r7, Bh.u[3], Bl.u[3]);
          bhi[nt] = Bh.s; blo[nt] = Bl.s;
        }
        #pragma unroll
        for (int mt = 0; mt < 2; ++mt)
          #pragma unroll
          for (int nt = 0; nt < 2; ++nt) {
            acc[mt][nt] = __builtin_amdgcn_mfma_f32_32x32x16_bf16(
                ahi[mt], bhi[nt], acc[mt][nt], 0, 0, 0);
            acc[mt][nt] = __builtin_amdgcn_mfma_f32_32x32x16_bf16(
                ahi[mt], blo[nt], acc[mt][nt], 0, 0, 0);
            acc[mt][nt] = __builtin_amdgcn_mfma_f32_32x32x16_bf16(
                alo[mt], bhi[nt], acc[mt][nt], 0, 0, 0);
          }
      }
      __syncthreads();
    } // dt

    #pragma unroll
    for (int mt = 0; mt < 2; ++mt) {
      #pragma unroll
      for (int r = 0; r < 16; ++r) {
        int row  = (r & 3) + 8 * (r >> 2) + 4 * lh;
        int code = kt * 128 + wm * 64 + mt * 32 + row;
        float ek = e2g[code];
        #pragma unroll
        for (int nt = 0; nt < 2; ++nt) {
          float s = 2.0f * acc[mt][nt][r] - ek;
          if (s > bestV[nt]) { bestV[nt] = s; bestI[nt] = code; }
        }
      }
    }
  } // kt

  __syncthreads();
  float* redV = Xraw;
  int*   redI = (int*)(Xraw + 512);
  int*   fIdx = (int*)(Xraw + 1024);

  #pragma unroll
  for (int nt = 0; nt < 2; ++nt) {
    int n = wn * 64 + nt * 32 + l31;
    int slot = lh + 2 * wm;
    redV[n * 4 + slot] = bestV[nt];
    redI[n * 4 + slot] = bestI[nt];
  }
  __syncthreads();
  if (t < 128) {
    float bv = redV[t * 4]; int bi = redI[t * 4];
    #pragma unroll
    for (int s = 1; s < 4; ++s) {
      float v = redV[t * 4 + s]; int ii = redI[t * 4 + s];
      if (v > bv || (v == bv && ii < bi)) { bv = v; bi = ii; }
    }
    fIdx[t] = bi;
    out[(size_t)B * D * N + (size_t)b * N + n0 + t] = (float)bi;
  }
  __syncthreads();

  {
    int n = t & 127;
    int code = fIdx[n];
    const float* erow = embed + (size_t)code * D;
    float* ob = out + (size_t)b * D * N + n0 + n;
    for (int d = (t >> 7); d < D; d += 2) {
      ob[(size_t)d * N] = erow[d];
    }
  }
}

extern "C" void kernel_launch(void* const* d_in, const int* in_sizes, int n_in,
                              void* d_out, int out_size, void* d_ws, size_t ws_size,
                              hipStream_t stream) {
  const float* x     = (const float*)d_in[0];
  const float* embed = (const float*)d_in[1];
  float* out = (float*)d_out;

  const size_t ES = (size_t)K * D;          // shorts per embed plane
  const size_t XS = (size_t)B * D * N;      // shorts per x plane
  const size_t need = 8192 + 2 * ES * 2 + 2 * XS * 2;  // 272,637,952 B

  float* e2 = (float*)d_ws;                 // 2048 floats (8 KB)

  if (ws_size >= need) {
    ushort* eh = (ushort*)((char*)d_ws + 8192);
    ushort* el = eh + ES;
    ushort* xhp = el + ES;
    ushort* xlp = xhp + XS;
    e2_kernel<<<dim3(K / 4), 256, 0, stream>>>(embed, e2);
    split_e<<<dim3(K / 16), 256, 0, stream>>>(embed, eh, el);
    split_x<<<dim3(N / 1024, D / 8, B), 256, 0, stream>>>(x, xhp, xlp);
    vq_mfma3<<<dim3(N / 256, B), 512, 0, stream>>>(xhp, xlp, eh, el, e2, embed, out);
  } else {
    e2_kernel<<<dim3(K / 4), 256, 0, stream>>>(embed, e2);
    vq_mfma<<<dim3(N / 128, B), 256, 0, stream>>>(x, embed, e2, out);
  }
}

// Round 3
// 1271.564 us; speedup vs baseline: 1.6537x; 1.0104x over previous
//
#include <hip/hip_runtime.h>
#include <math.h>
#include <stdint.h>

// VectorQuantization, round 5: counted-vmcnt pipeline (T3+T4) + setprio (T5).
// Same 256c x 256n geometry as round 4; the change is the sync structure:
// raw s_barrier + s_waitcnt vmcnt(8) (never 0 in main loop) instead of
// __syncthreads' vmcnt(0) drain. Loads for step s+2 stay in flight across
// the buffer-swap barrier.
// x: [B=16, D=512, N=8192] fp32, embed: [K=2048, D=512] fp32.
// out = quantize [B,D,N] fp32 ++ embed_ind [B,N] as fp32.
// MFMA floor: 3*2.75e11 FLOP / 2.5 PF = 330 us.

constexpr int B = 16, D = 512, N = 8192, K = 2048;

typedef __attribute__((ext_vector_type(8)))  short   short8;    // bf16x8 frag
typedef __attribute__((ext_vector_type(16))) float   floatx16;  // 32x32 acc

typedef const __attribute__((address_space(1))) uint32_t* gas1_t;
typedef __attribute__((address_space(3)))       uint32_t* las3_t;

__device__ __forceinline__ void async_ld16(const void* g, void* lds) {
  // 16B per lane, LDS dest = wave-uniform base + lane*16
  __builtin_amdgcn_global_load_lds((gas1_t)g, (las3_t)lds, 16, 0, 0);
}

__device__ __forceinline__ uint32_t rne_hi(float a) {
  uint32_t u = __float_as_uint(a);
  return (u + 0x7fffu + ((u >> 16) & 1u)) & 0xffff0000u;
}

// split pair (a,b) -> hi = packed(bf16(a), bf16(b)), lo = packed residuals
__device__ __forceinline__ void split2(float a, float b, uint32_t& hi, uint32_t& lo) {
  uint32_t ha = rne_hi(a), hb = rne_hi(b);
  float ra = a - __uint_as_float(ha);
  float rb = b - __uint_as_float(hb);
  hi = (ha >> 16) | hb;
  uint32_t la = rne_hi(ra), lb = rne_hi(rb);
  lo = (la >> 16) | lb;
}

// ---- kernel: e2[k] = sum_d embed[k][d]^2 ----
__global__ __launch_bounds__(256) void e2_kernel(const float* __restrict__ embed,
                                                 float* __restrict__ e2) {
  int k = blockIdx.x * 4 + (threadIdx.x >> 6);
  int lane = threadIdx.x & 63;
  const float* row = embed + (size_t)k * D;
  float s = 0.f;
  #pragma unroll
  for (int d = 0; d < D; d += 64) {
    float v = row[d + lane];
    s = fmaf(v, v, s);
  }
  #pragma unroll
  for (int off = 32; off; off >>= 1) s += __shfl_down(s, off, 64);
  if (lane == 0) e2[k] = s;
}

// ---- pre-pass: split x into bf16 hi/lo, per-step LDS-image layout ----
// Plane layout: [(b*32 + n/256)*16 + d/32] tiles of 8192 shorts,
// tile = [run=(d>>3)&3][n&255][d&7].
__global__ __launch_bounds__(256) void split_x(const float* __restrict__ x,
                                               ushort* __restrict__ xh,
                                               ushort* __restrict__ xl) {
  const int t  = threadIdx.x;
  const int n0 = blockIdx.x * 1024 + t * 4;
  const int g  = blockIdx.y;            // d-group of 8 (0..63)
  const int b  = blockIdx.z;
  const float* src = x + ((size_t)b * D + g * 8) * N + n0;
  union { ushort u[8]; short8 s; } H[4], L[4];
  #pragma unroll
  for (int r = 0; r < 8; ++r) {
    const float4 v = *(const float4*)(src + (size_t)r * N);  // 16B/lane coalesced
    const float a0 = v.x, a1 = v.y, a2 = v.z, a3 = v.w;
    uint32_t h; float res;
    h = rne_hi(a0); res = a0 - __uint_as_float(h); H[0].u[r] = (ushort)(h >> 16); L[0].u[r] = (ushort)(rne_hi(res) >> 16);
    h = rne_hi(a1); res = a1 - __uint_as_float(h); H[1].u[r] = (ushort)(h >> 16); L[1].u[r] = (ushort)(rne_hi(res) >> 16);
    h = rne_hi(a2); res = a2 - __uint_as_float(h); H[2].u[r] = (ushort)(h >> 16); L[2].u[r] = (ushort)(rne_hi(res) >> 16);
    h = rne_hi(a3); res = a3 - __uint_as_float(h); H[3].u[r] = (ushort)(h >> 16); L[3].u[r] = (ushort)(rne_hi(res) >> 16);
  }
  const size_t base = ((size_t)(b * 32 + (n0 >> 8)) * 16 + (g >> 2)) * 8192
                    + ((size_t)(g & 3) * 256 + (n0 & 255)) * 8;
  #pragma unroll
  for (int j = 0; j < 4; ++j) {         // 64B contiguous per lane, coalesced
    *(short8*)&xh[base + j * 8] = H[j].s;
    *(short8*)&xl[base + j * 8] = L[j].s;
  }
}

// ---- pre-pass: split embed, tiles [(c/256)*16 + d/32] of [run][c&255][d&7] ----
__global__ __launch_bounds__(256) void split_e(const float* __restrict__ embed,
                                               ushort* __restrict__ eh,
                                               ushort* __restrict__ el) {
  const int t = threadIdx.x;
  const int c = blockIdx.x * 16 + (t >> 4);
  const int kt2 = c >> 8, cl = c & 255;
  #pragma unroll
  for (int p = 0; p < 8; ++p) {
    int d0 = p * 64 + (t & 15) * 4;
    const float4 v = *(const float4*)(embed + (size_t)c * D + d0);
    uint32_t h0, l0, h1, l1;
    split2(v.x, v.y, h0, l0);
    split2(v.z, v.w, h1, l1);
    int dt2 = d0 >> 5, run = (d0 >> 3) & 3, e = d0 & 7;   // e in {0,4}
    size_t off = (size_t)(kt2 * 16 + dt2) * 8192 + ((size_t)run * 256 + cl) * 8 + e;
    *(uint2*)&eh[off] = make_uint2(h0, h1);
    *(uint2*)&el[off] = make_uint2(l0, l1);
  }
}

// ---- main kernel: 256c x 256n per block, counted-vmcnt 2-buffer pipeline ----
__global__ __launch_bounds__(512, 2) void vq_mfma4(const ushort* __restrict__ xh,
                                                   const ushort* __restrict__ xl,
                                                   const ushort* __restrict__ eh,
                                                   const ushort* __restrict__ el,
                                                   const float* __restrict__ e2g,
                                                   const float* __restrict__ embed,
                                                   float* __restrict__ out) {
  // LDS: 4 planes x dbuf x 16KB = 128 KB + 9.25 KB reduction = 137.25 KB -> 1 blk/CU
  __shared__ ushort Xh[2][8192], Xl[2][8192];   // [buf][run4][n256][8]
  __shared__ ushort Eh[2][8192], El[2][8192];   // [buf][run4][c256][8]
  __shared__ float redV[1024];
  __shared__ int   redI[1024];
  __shared__ int   fIdx[256];

  const int t    = threadIdx.x;
  const int lane = t & 63;
  const int wid  = t >> 6;     // 0..7
  const int wm   = wid & 1;    // code-dim wave coord (2 x 128 codes)
  const int wn   = wid >> 1;   // n-dim wave coord (4 x 64 n)
  const int l31  = lane & 31;
  const int lh   = lane >> 5;  // half-wave

  const int b  = blockIdx.y;
  const int nb = blockIdx.x;
  const int n0 = nb * 256;

  const size_t xbase = (size_t)(b * 32 + nb) * 16 * 8192;  // shorts

  float bestV[2] = {-3.402823466e38f, -3.402823466e38f};
  int   bestI[2] = {0, 0};

  floatx16 acc[4][2];
  #pragma unroll
  for (int mt = 0; mt < 4; ++mt)
    #pragma unroll
    for (int nt = 0; nt < 2; ++nt)
      #pragma unroll
      for (int i = 0; i < 16; ++i) acc[mt][nt][i] = 0.f;

  // stage step s (kt2 = s>>4, dt2 = s&15) into buffer `buf`:
  // 64 KB block-wide, 8 global_load_lds per wave (vmcnt batch of 8)
  auto STAGE = [&](int s, int buf) {
    const int kt2 = s >> 4, dt2 = s & 15;
    const size_t xo = xbase + (size_t)dt2 * 8192;
    const size_t eo = (size_t)(kt2 * 16 + dt2) * 8192;
    #pragma unroll
    for (int i = 0; i < 2; ++i) {
      const int o = (wid * 2 + i) * 512;   // shorts; 1 KB per instruction
      async_ld16(xh + xo + o + lane * 8, &Xh[buf][o]);
      async_ld16(xl + xo + o + lane * 8, &Xl[buf][o]);
      async_ld16(eh + eo + o + lane * 8, &Eh[buf][o]);
      async_ld16(el + eo + o + lane * 8, &El[buf][o]);
    }
  };

  // prologue: fill both buffers, wait only for buf0 (8 newest stay in flight)
  STAGE(0, 0);
  STAGE(1, 1);
  asm volatile("s_waitcnt vmcnt(8)" ::: "memory");
  __builtin_amdgcn_s_barrier();
  __builtin_amdgcn_sched_barrier(0);

  int cur = 0;
  for (int s = 0; s < 128; ++s) {
    // ---- compute on buf[cur]; buf[cur^1] loads still in flight ----
    #pragma unroll
    for (int ks = 0; ks < 2; ++ks) {
      const int run = ks * 2 + lh;
      short8 ah[4], al[4];
      #pragma unroll
      for (int mt = 0; mt < 4; ++mt) {
        const int eoff = (run * 256 + (wm * 128 + mt * 32 + l31)) * 8;
        ah[mt] = *(const short8*)&Eh[cur][eoff];
        al[mt] = *(const short8*)&El[cur][eoff];
      }
      short8 bh[2], bl[2];
      #pragma unroll
      for (int nt = 0; nt < 2; ++nt) {
        const int xoff = (run * 256 + (wn * 64 + nt * 32 + l31)) * 8;
        bh[nt] = *(const short8*)&Xh[cur][xoff];
        bl[nt] = *(const short8*)&Xl[cur][xoff];
      }
      __builtin_amdgcn_s_setprio(1);
      #pragma unroll
      for (int mt = 0; mt < 4; ++mt)
        #pragma unroll
        for (int nt = 0; nt < 2; ++nt) {
          acc[mt][nt] = __builtin_amdgcn_mfma_f32_32x32x16_bf16(
              ah[mt], bh[nt], acc[mt][nt], 0, 0, 0);
          acc[mt][nt] = __builtin_amdgcn_mfma_f32_32x32x16_bf16(
              ah[mt], bl[nt], acc[mt][nt], 0, 0, 0);
          acc[mt][nt] = __builtin_amdgcn_mfma_f32_32x32x16_bf16(
              al[mt], bh[nt], acc[mt][nt], 0, 0, 0);
        }
      __builtin_amdgcn_s_setprio(0);
    }

    if ((s & 15) == 15) {   // end of a 256-code tile: fold argmax, reset acc
      const int kt2 = s >> 4;
      #pragma unroll
      for (int mt = 0; mt < 4; ++mt) {
        #pragma unroll
        for (int r = 0; r < 16; ++r) {
          const int row  = (r & 3) + 8 * (r >> 2) + 4 * lh;
          const int code = kt2 * 256 + wm * 128 + mt * 32 + row;
          const float ek = e2g[code];
          #pragma unroll
          for (int nt = 0; nt < 2; ++nt) {
            const float sv = 2.0f * acc[mt][nt][r] - ek;
            if (sv > bestV[nt]) { bestV[nt] = sv; bestI[nt] = code; }
            acc[mt][nt][r] = 0.f;
          }
        }
      }
    }

    // ---- B1: all waves done reading buf[cur]; safe to overwrite ----
    __builtin_amdgcn_sched_barrier(0);
    __builtin_amdgcn_s_barrier();
    __builtin_amdgcn_sched_barrier(0);

    if (s <= 125) {
      STAGE(s + 2, cur);                       // 8 new loads into just-freed buf
      // wait for the PREVIOUS batch (buf[cur^1], issued one full step ago);
      // the 8 just-issued stay in flight across the barrier.
      asm volatile("s_waitcnt vmcnt(8)" ::: "memory");
    } else {
      asm volatile("s_waitcnt vmcnt(0)" ::: "memory");   // tail drain
    }

    // ---- B2: buf[cur^1] ready for everyone ----
    __builtin_amdgcn_s_barrier();
    __builtin_amdgcn_sched_barrier(0);
    cur ^= 1;
  }

  // ---- cross-wave reduction: 4 candidates per n (lh x wm) ----
  __syncthreads();
  #pragma unroll
  for (int nt = 0; nt < 2; ++nt) {
    const int n = wn * 64 + nt * 32 + l31;
    const int slot = lh * 2 + wm;
    redV[n * 4 + slot] = bestV[nt];
    redI[n * 4 + slot] = bestI[nt];
  }
  __syncthreads();
  if (t < 256) {
    float bv = redV[t * 4]; int bi = redI[t * 4];
    #pragma unroll
    for (int s = 1; s < 4; ++s) {
      float v = redV[t * 4 + s]; int ii = redI[t * 4 + s];
      if (v > bv || (v == bv && ii < bi)) { bv = v; bi = ii; }
    }
    fIdx[t] = bi;
    out[(size_t)B * D * N + (size_t)b * N + n0 + t] = (float)bi;
  }
  __syncthreads();

  // ---- fused gather: out[b][d][n0+n] = embed[fIdx[n]][d] ----
  {
    const int n = t & 255;
    const int code = fIdx[n];
    const float* erow = embed + (size_t)code * D;
    float* ob = out + (size_t)b * D * N + n0 + n;
    for (int d = (t >> 8); d < D; d += 2) {
      ob[(size_t)d * N] = erow[d];
    }
  }
}

// ===================== fallback path (round-2 kernel, small ws) =====================
__global__ __launch_bounds__(256, 2) void vq_mfma(const float* __restrict__ x,
                                                  const float* __restrict__ embed,
                                                  const float* __restrict__ e2g,
                                                  float* __restrict__ out) {
  __shared__ float    Xraw[64 * 128];
  __shared__ uint16_t Ehi[128 * 64];
  __shared__ uint16_t Elo[128 * 64];

  const int t    = threadIdx.x;
  const int lane = t & 63;
  const int wid  = t >> 6;
  const int wm   = wid & 1;
  const int wn   = wid >> 1;
  const int l31  = lane & 31;
  const int lh   = lane >> 5;

  const int b  = blockIdx.y;
  const int n0 = blockIdx.x * 128;
  const float* xb = x + (size_t)b * D * N + n0;

  float bestV[2] = {-3.402823466e38f, -3.402823466e38f};
  int   bestI[2] = {0, 0};

  for (int kt = 0; kt < K / 128; ++kt) {
    floatx16 acc[2][2];
    #pragma unroll
    for (int mt = 0; mt < 2; ++mt)
      #pragma unroll
      for (int nt = 0; nt < 2; ++nt)
        #pragma unroll
        for (int i = 0; i < 16; ++i) acc[mt][nt][i] = 0.f;

    for (int dt = 0; dt < D / 64; ++dt) {
      {
        const float* g0 = xb + (size_t)(dt * 64 + wid * 16 + lh) * N + l31 * 4;
        #pragma unroll
        for (int i = 0; i < 8; ++i) {
          async_ld16(g0 + (size_t)(i * 2) * N, &Xraw[(wid * 16 + i * 2) * 128]);
        }
      }
      {
        const float* eb = embed + (size_t)(kt * 128) * D + dt * 64;
        const int f4 = t & 15;
        const int cr = t >> 4;
        #pragma unroll
        for (int p = 0; p < 8; ++p) {
          int c = p * 16 + cr;
          const float4 v = *(const float4*)(eb + (size_t)c * D + f4 * 4);
          uint32_t h0, l0, h1, l1;
          split2(v.x, v.y, h0, l0);
          split2(v.z, v.w, h1, l1);
          int run = f4 >> 1, half = f4 & 1;
          int off = ((run ^ (c & 7)) * 8 + half * 4);
          *(uint2*)&Ehi[c * 64 + off] = make_uint2(h0, h1);
          *(uint2*)&Elo[c * 64 + off] = make_uint2(l0, l1);
        }
      }
      __syncthreads();

      #pragma unroll
      for (int ks = 0; ks < 4; ++ks) {
        short8 ahi[2], alo[2];
        #pragma unroll
        for (int mt = 0; mt < 2; ++mt) {
          int c = wm * 64 + mt * 32 + l31;
          int run = ks * 2 + lh;
          int off = (run ^ (c & 7)) * 8;
          ahi[mt] = *(const short8*)&Ehi[c * 64 + off];
          alo[mt] = *(const short8*)&Elo[c * 64 + off];
        }
        short8 bhi[2], blo[2];
        #pragma unroll
        for (int nt = 0; nt < 2; ++nt) {
          int n = wn * 64 + nt * 32 + l31;
          int kb = ks * 16 + lh * 8;
          float r0 = Xraw[(kb + 0) * 128 + n];
          float r1 = Xraw[(kb + 1) * 128 + n];
          float r2 = Xraw[(kb + 2) * 128 + n];
          float r3 = Xraw[(kb + 3) * 128 + n];
          float r4 = Xraw[(kb + 4) * 128 + n];
          float r5 = Xraw[(kb + 5) * 128 + n];
          float r6 = Xraw[(kb + 6) * 128 + n];
          float r7 = Xraw[(kb + 7) * 128 + n];
          union { short8 s; uint32_t u[4]; } Bh, Bl;
          split2(r0, r1, Bh.u[0], Bl.u[0]);
          split2(r2, r3, Bh.u[1], Bl.u[1]);
          split2(r4, r5, Bh.u[2], Bl.u[2]);
          split2(r6, r7, Bh.u[3], Bl.u[3]);
          bhi[nt] = Bh.s; blo[nt] = Bl.s;
        }
        #pragma unroll
        for (int mt = 0; mt < 2; ++mt)
          #pragma unroll
          for (int nt = 0; nt < 2; ++nt) {
            acc[mt][nt] = __builtin_amdgcn_mfma_f32_32x32x16_bf16(
                ahi[mt], bhi[nt], acc[mt][nt], 0, 0, 0);
            acc[mt][nt] = __builtin_amdgcn_mfma_f32_32x32x16_bf16(
                ahi[mt], blo[nt], acc[mt][nt], 0, 0, 0);
            acc[mt][nt] = __builtin_amdgcn_mfma_f32_32x32x16_bf16(
                alo[mt], bhi[nt], acc[mt][nt], 0, 0, 0);
          }
      }
      __syncthreads();
    } // dt

    #pragma unroll
    for (int mt = 0; mt < 2; ++mt) {
      #pragma unroll
      for (int r = 0; r < 16; ++r) {
        int row  = (r & 3) + 8 * (r >> 2) + 4 * lh;
        int code = kt * 128 + wm * 64 + mt * 32 + row;
        float ek = e2g[code];
        #pragma unroll
        for (int nt = 0; nt < 2; ++nt) {
          float s = 2.0f * acc[mt][nt][r] - ek;
          if (s > bestV[nt]) { bestV[nt] = s; bestI[nt] = code; }
        }
      }
    }
  } // kt

  __syncthreads();
  float* redV = Xraw;
  int*   redI = (int*)(Xraw + 512);
  int*   fIdx = (int*)(Xraw + 1024);

  #pragma unroll
  for (int nt = 0; nt < 2; ++nt) {
    int n = wn * 64 + nt * 32 + l31;
    int slot = lh + 2 * wm;
    redV[n * 4 + slot] = bestV[nt];
    redI[n * 4 + slot] = bestI[nt];
  }
  __syncthreads();
  if (t < 128) {
    float bv = redV[t * 4]; int bi = redI[t * 4];
    #pragma unroll
    for (int s = 1; s < 4; ++s) {
      float v = redV[t * 4 + s]; int ii = redI[t * 4 + s];
      if (v > bv || (v == bv && ii < bi)) { bv = v; bi = ii; }
    }
    fIdx[t] = bi;
    out[(size_t)B * D * N + (size_t)b * N + n0 + t] = (float)bi;
  }
  __syncthreads();

  {
    int n = t & 127;
    int code = fIdx[n];
    const float* erow = embed + (size_t)code * D;
    float* ob = out + (size_t)b * D * N + n0 + n;
    for (int d = (t >> 7); d < D; d += 2) {
      ob[(size_t)d * N] = erow[d];
    }
  }
}

extern "C" void kernel_launch(void* const* d_in, const int* in_sizes, int n_in,
                              void* d_out, int out_size, void* d_ws, size_t ws_size,
                              hipStream_t stream) {
  const float* x     = (const float*)d_in[0];
  const float* embed = (const float*)d_in[1];
  float* out = (float*)d_out;

  const size_t ES = (size_t)K * D;          // shorts per embed plane
  const size_t XS = (size_t)B * D * N;      // shorts per x plane
  const size_t need = 8192 + 2 * ES * 2 + 2 * XS * 2;  // 272,637,952 B

  float* e2 = (float*)d_ws;                 // 2048 floats (8 KB)

  if (ws_size >= need) {
    ushort* eh = (ushort*)((char*)d_ws + 8192);
    ushort* el = eh + ES;
    ushort* xhp = el + ES;
    ushort* xlp = xhp + XS;
    e2_kernel<<<dim3(K / 4), 256, 0, stream>>>(embed, e2);
    split_e<<<dim3(K / 16), 256, 0, stream>>>(embed, eh, el);
    split_x<<<dim3(N / 1024, D / 8, B), 256, 0, stream>>>(x, xhp, xlp);
    vq_mfma4<<<dim3(N / 256, B), 512, 0, stream>>>(xhp, xlp, eh, el, e2, embed, out);
  } else {
    e2_kernel<<<dim3(K / 4), 256, 0, stream>>>(embed, e2);
    vq_mfma<<<dim3(N / 128, B), 256, 0, stream>>>(x, embed, e2, out);
  }
}

// Round 4
// 1226.875 us; speedup vs baseline: 1.7140x; 1.0364x over previous
//
#include <hip/hip_runtime.h>
#include <math.h>
#include <stdint.h>

// VectorQuantization, round 6: faithful 8-phase-template port (m201-style).
// Ring of 4 half-buffers (16 d = 32 KB each), 2 phases per half-step
// {ds_read frags + 2 global_load_lds + s_barrier + lgkmcnt(0) + 12-MFMA
// setprio cluster + s_barrier}, staging 3 half-units ahead, vmcnt(8) once
// per half-step (never 0 in steady state). e2 preloaded to LDS so the main
// loop has ZERO non-staging VMEM (keeps vmcnt discipline clean).
// x: [B=16, D=512, N=8192] fp32, embed: [K=2048, D=512] fp32.
// out = quantize [B,D,N] fp32 ++ embed_ind [B,N] as fp32.
// MFMA floor: 3*2.75e11 FLOP / 2.5 PF = 330 us.

constexpr int B = 16, D = 512, N = 8192, K = 2048;

typedef __attribute__((ext_vector_type(8)))  short   short8;    // bf16x8 frag
typedef __attribute__((ext_vector_type(16))) float   floatx16;  // 32x32 acc

typedef const __attribute__((address_space(1))) uint32_t* gas1_t;
typedef __attribute__((address_space(3)))       uint32_t* las3_t;

__device__ __forceinline__ void async_ld16(const void* g, void* lds) {
  // 16B per lane, LDS dest = wave-uniform base + lane*16
  __builtin_amdgcn_global_load_lds((gas1_t)g, (las3_t)lds, 16, 0, 0);
}

__device__ __forceinline__ uint32_t rne_hi(float a) {
  uint32_t u = __float_as_uint(a);
  return (u + 0x7fffu + ((u >> 16) & 1u)) & 0xffff0000u;
}

// split pair (a,b) -> hi = packed(bf16(a), bf16(b)), lo = packed residuals
__device__ __forceinline__ void split2(float a, float b, uint32_t& hi, uint32_t& lo) {
  uint32_t ha = rne_hi(a), hb = rne_hi(b);
  float ra = a - __uint_as_float(ha);
  float rb = b - __uint_as_float(hb);
  hi = (ha >> 16) | hb;
  uint32_t la = rne_hi(ra), lb = rne_hi(rb);
  lo = (la >> 16) | lb;
}

// ---- kernel: e2[k] = sum_d embed[k][d]^2 ----
__global__ __launch_bounds__(256) void e2_kernel(const float* __restrict__ embed,
                                                 float* __restrict__ e2) {
  int k = blockIdx.x * 4 + (threadIdx.x >> 6);
  int lane = threadIdx.x & 63;
  const float* row = embed + (size_t)k * D;
  float s = 0.f;
  #pragma unroll
  for (int d = 0; d < D; d += 64) {
    float v = row[d + lane];
    s = fmaf(v, v, s);
  }
  #pragma unroll
  for (int off = 32; off; off >>= 1) s += __shfl_down(s, off, 64);
  if (lane == 0) e2[k] = s;
}

// ---- pre-pass: split x into bf16 hi/lo, per-step LDS-image layout ----
// Plane layout: [(b*32 + n/256)*16 + d/32] tiles of 8192 shorts,
// tile = [run=(d>>3)&3][n&255][d&7].
__global__ __launch_bounds__(256) void split_x(const float* __restrict__ x,
                                               ushort* __restrict__ xh,
                                               ushort* __restrict__ xl) {
  const int t  = threadIdx.x;
  const int n0 = blockIdx.x * 1024 + t * 4;
  const int g  = blockIdx.y;            // d-group of 8 (0..63)
  const int b  = blockIdx.z;
  const float* src = x + ((size_t)b * D + g * 8) * N + n0;
  union { ushort u[8]; short8 s; } H[4], L[4];
  #pragma unroll
  for (int r = 0; r < 8; ++r) {
    const float4 v = *(const float4*)(src + (size_t)r * N);  // 16B/lane coalesced
    const float a0 = v.x, a1 = v.y, a2 = v.z, a3 = v.w;
    uint32_t h; float res;
    h = rne_hi(a0); res = a0 - __uint_as_float(h); H[0].u[r] = (ushort)(h >> 16); L[0].u[r] = (ushort)(rne_hi(res) >> 16);
    h = rne_hi(a1); res = a1 - __uint_as_float(h); H[1].u[r] = (ushort)(h >> 16); L[1].u[r] = (ushort)(rne_hi(res) >> 16);
    h = rne_hi(a2); res = a2 - __uint_as_float(h); H[2].u[r] = (ushort)(h >> 16); L[2].u[r] = (ushort)(rne_hi(res) >> 16);
    h = rne_hi(a3); res = a3 - __uint_as_float(h); H[3].u[r] = (ushort)(h >> 16); L[3].u[r] = (ushort)(rne_hi(res) >> 16);
  }
  const size_t base = ((size_t)(b * 32 + (n0 >> 8)) * 16 + (g >> 2)) * 8192
                    + ((size_t)(g & 3) * 256 + (n0 & 255)) * 8;
  #pragma unroll
  for (int j = 0; j < 4; ++j) {         // 64B contiguous per lane, coalesced
    *(short8*)&xh[base + j * 8] = H[j].s;
    *(short8*)&xl[base + j * 8] = L[j].s;
  }
}

// ---- pre-pass: split embed, tiles [(c/256)*16 + d/32] of [run][c&255][d&7] ----
__global__ __launch_bounds__(256) void split_e(const float* __restrict__ embed,
                                               ushort* __restrict__ eh,
                                               ushort* __restrict__ el) {
  const int t = threadIdx.x;
  const int c = blockIdx.x * 16 + (t >> 4);
  const int kt2 = c >> 8, cl = c & 255;
  #pragma unroll
  for (int p = 0; p < 8; ++p) {
    int d0 = p * 64 + (t & 15) * 4;
    const float4 v = *(const float4*)(embed + (size_t)c * D + d0);
    uint32_t h0, l0, h1, l1;
    split2(v.x, v.y, h0, l0);
    split2(v.z, v.w, h1, l1);
    int dt2 = d0 >> 5, run = (d0 >> 3) & 3, e = d0 & 7;   // e in {0,4}
    size_t off = (size_t)(kt2 * 16 + dt2) * 8192 + ((size_t)run * 256 + cl) * 8 + e;
    *(uint2*)&eh[off] = make_uint2(h0, h1);
    *(uint2*)&el[off] = make_uint2(l0, l1);
  }
}

// ---- main kernel: 256c x 256n, 8-phase ring pipeline ----
__global__ __launch_bounds__(512, 2) void vq_mfma5(const ushort* __restrict__ xh,
                                                   const ushort* __restrict__ xl,
                                                   const ushort* __restrict__ eh,
                                                   const ushort* __restrict__ el,
                                                   const float* __restrict__ e2g,
                                                   const float* __restrict__ embed,
                                                   float* __restrict__ out) {
  // LDS: 4 rings x 4 half-planes x 8KB = 128 KB + e2 8KB + red 9KB = 145 KB
  __shared__ ushort XhL[16384], XlL[16384];   // [ring4][run2][n256][8]
  __shared__ ushort EhL[16384], ElL[16384];   // [ring4][run2][c256][8]
  __shared__ float  e2L[2048];
  __shared__ float  redV[1024];
  __shared__ int    redI[1024];
  __shared__ int    fIdx[256];

  const int t    = threadIdx.x;
  const int lane = t & 63;
  const int wid  = t >> 6;     // 0..7
  const int wm   = wid & 1;    // code-dim wave coord (2 x 128 codes)
  const int wn   = wid >> 1;   // n-dim wave coord (4 x 64 n)
  const int l31  = lane & 31;
  const int lh   = lane >> 5;  // half-wave -> run within half-unit

  const int b  = blockIdx.y;
  const int nb = blockIdx.x;
  const int n0 = nb * 256;

  const size_t xbase = (size_t)(b * 32 + nb) * 16 * 8192;  // shorts

  // e2 -> LDS once; keeps the main loop free of non-staging VMEM.
  #pragma unroll
  for (int i = 0; i < 4; ++i) e2L[t + i * 512] = e2g[t + i * 512];
  __syncthreads();

  float bestV[2] = {-3.402823466e38f, -3.402823466e38f};
  int   bestI[2] = {0, 0};

  floatx16 acc[4][2];
  #pragma unroll
  for (int mt = 0; mt < 4; ++mt)
    #pragma unroll
    for (int nt = 0; nt < 2; ++nt)
      #pragma unroll
      for (int i = 0; i < 16; ++i) acc[mt][nt][i] = 0.f;

  // half-unit u (0..255): kt2 = u>>5, dt2 = (u>>1)&15, ks = u&1.
  // Stage X planes (2 gloads) in phase A, E planes (2) in phase B -> 4/unit.
  auto STAGE_X = [&](int up) {
    const int dt2 = (up >> 1) & 15, ks = up & 1, hb = up & 3;
    const size_t so = xbase + (size_t)dt2 * 8192 + ks * 4096 + wid * 512 + lane * 8;
    async_ld16(xh + so, &XhL[hb * 4096 + wid * 512]);
    async_ld16(xl + so, &XlL[hb * 4096 + wid * 512]);
  };
  auto STAGE_E = [&](int up) {
    const int kt2 = up >> 5, dt2 = (up >> 1) & 15, ks = up & 1, hb = up & 3;
    const size_t so = (size_t)(kt2 * 16 + dt2) * 8192 + ks * 4096 + wid * 512 + lane * 8;
    async_ld16(eh + so, &EhL[hb * 4096 + wid * 512]);
    async_ld16(el + so, &ElL[hb * 4096 + wid * 512]);
  };

  // prologue: stage u = 0,1,2 (3 batches x 4 gloads); wait only batch 0
  STAGE_X(0); STAGE_E(0);
  STAGE_X(1); STAGE_E(1);
  STAGE_X(2); STAGE_E(2);
  asm volatile("s_waitcnt vmcnt(8)" ::: "memory");
  __builtin_amdgcn_s_barrier();
  __builtin_amdgcn_sched_barrier(0);

  // per-lane invariant fragment offsets (shorts)
  const int rb   = lh * 2048;                       // run within half-unit
  const int xo0  = rb + (wn * 64 + l31) * 8;        // nt=0 (nt stride 256)
  const int ao0  = rb + (wm * 128 + l31) * 8;       // mt=0 (mt stride 256)

  for (int u = 0; u < 256; ++u) {
    const int hb4 = (u & 3) * 4096;

    // ================= phase A : quadrant mt={0,1} =================
    short8 bh[2], bl[2], a0h[2], a0l[2];
    #pragma unroll
    for (int nt = 0; nt < 2; ++nt) {
      const int xo = hb4 + xo0 + nt * 256;
      bh[nt] = *(const short8*)&XhL[xo];
      bl[nt] = *(const short8*)&XlL[xo];
    }
    #pragma unroll
    for (int m2 = 0; m2 < 2; ++m2) {
      const int eo = hb4 + ao0 + m2 * 256;
      a0h[m2] = *(const short8*)&EhL[eo];
      a0l[m2] = *(const short8*)&ElL[eo];
    }
    if (u <= 252) STAGE_X(u + 3);
    __builtin_amdgcn_s_barrier();
    asm volatile("s_waitcnt lgkmcnt(0)" ::: "memory");
    __builtin_amdgcn_sched_barrier(0);
    __builtin_amdgcn_s_setprio(1);
    #pragma unroll
    for (int m2 = 0; m2 < 2; ++m2)
      #pragma unroll
      for (int nt = 0; nt < 2; ++nt) {
        acc[m2][nt] = __builtin_amdgcn_mfma_f32_32x32x16_bf16(
            a0h[m2], bh[nt], acc[m2][nt], 0, 0, 0);
        acc[m2][nt] = __builtin_amdgcn_mfma_f32_32x32x16_bf16(
            a0h[m2], bl[nt], acc[m2][nt], 0, 0, 0);
        acc[m2][nt] = __builtin_amdgcn_mfma_f32_32x32x16_bf16(
            a0l[m2], bh[nt], acc[m2][nt], 0, 0, 0);
      }
    __builtin_amdgcn_s_setprio(0);
    __builtin_amdgcn_s_barrier();

    // ================= phase B : quadrant mt={2,3} =================
    short8 a1h[2], a1l[2];
    #pragma unroll
    for (int m2 = 0; m2 < 2; ++m2) {
      const int eo = hb4 + ao0 + (2 + m2) * 256;
      a1h[m2] = *(const short8*)&EhL[eo];
      a1l[m2] = *(const short8*)&ElL[eo];
    }
    if (u <= 252) STAGE_E(u + 3);
    __builtin_amdgcn_s_barrier();
    asm volatile("s_waitcnt lgkmcnt(0)" ::: "memory");
    __builtin_amdgcn_sched_barrier(0);
    __builtin_amdgcn_s_setprio(1);
    #pragma unroll
    for (int m2 = 0; m2 < 2; ++m2)
      #pragma unroll
      for (int nt = 0; nt < 2; ++nt) {
        acc[2 + m2][nt] = __builtin_amdgcn_mfma_f32_32x32x16_bf16(
            a1h[m2], bh[nt], acc[2 + m2][nt], 0, 0, 0);
        acc[2 + m2][nt] = __builtin_amdgcn_mfma_f32_32x32x16_bf16(
            a1h[m2], bl[nt], acc[2 + m2][nt], 0, 0, 0);
        acc[2 + m2][nt] = __builtin_amdgcn_mfma_f32_32x32x16_bf16(
            a1l[m2], bh[nt], acc[2 + m2][nt], 0, 0, 0);
      }
    __builtin_amdgcn_s_setprio(0);

    if ((u & 31) == 31) {   // end of a 256-code tile: fold argmax, reset acc
      const int kt2 = u >> 5;
      #pragma unroll
      for (int mt = 0; mt < 4; ++mt) {
        #pragma unroll
        for (int r = 0; r < 16; ++r) {
          const int row  = (r & 3) + 8 * (r >> 2) + 4 * lh;
          const int code = kt2 * 256 + wm * 128 + mt * 32 + row;
          const float ek = e2L[code];                 // LDS, no VMEM
          #pragma unroll
          for (int nt = 0; nt < 2; ++nt) {
            const float sv = 2.0f * acc[mt][nt][r] - ek;
            if (sv > bestV[nt]) { bestV[nt] = sv; bestI[nt] = code; }
            acc[mt][nt][r] = 0.f;
          }
        }
      }
    }

    // counted wait: batch u+1 (issued during u-2) must be done; newest
    // two batches (u+2, u+3) stay in flight across the barrier.
    if (u <= 252) {
      asm volatile("s_waitcnt vmcnt(8)" ::: "memory");
    } else {
      asm volatile("s_waitcnt vmcnt(0)" ::: "memory");   // tail drain
    }
    __builtin_amdgcn_s_barrier();
    __builtin_amdgcn_sched_barrier(0);
  }

  // ---- cross-wave reduction: 4 candidates per n (lh x wm) ----
  __syncthreads();
  #pragma unroll
  for (int nt = 0; nt < 2; ++nt) {
    const int n = wn * 64 + nt * 32 + l31;
    const int slot = lh * 2 + wm;
    redV[n * 4 + slot] = bestV[nt];
    redI[n * 4 + slot] = bestI[nt];
  }
  __syncthreads();
  if (t < 256) {
    float bv = redV[t * 4]; int bi = redI[t * 4];
    #pragma unroll
    for (int s = 1; s < 4; ++s) {
      float v = redV[t * 4 + s]; int ii = redI[t * 4 + s];
      if (v > bv || (v == bv && ii < bi)) { bv = v; bi = ii; }
    }
    fIdx[t] = bi;
    out[(size_t)B * D * N + (size_t)b * N + n0 + t] = (float)bi;
  }
  __syncthreads();

  // ---- fused gather: out[b][d][n0+n] = embed[fIdx[n]][d] ----
  {
    const int n = t & 255;
    const int code = fIdx[n];
    const float* erow = embed + (size_t)code * D;
    float* ob = out + (size_t)b * D * N + n0 + n;
    for (int d = (t >> 8); d < D; d += 2) {
      ob[(size_t)d * N] = erow[d];
    }
  }
}

// ===================== fallback path (round-2 kernel, small ws) =====================
__global__ __launch_bounds__(256, 2) void vq_mfma(const float* __restrict__ x,
                                                  const float* __restrict__ embed,
                                                  const float* __restrict__ e2g,
                                                  float* __restrict__ out) {
  __shared__ float    Xraw[64 * 128];
  __shared__ uint16_t Ehi[128 * 64];
  __shared__ uint16_t Elo[128 * 64];

  const int t    = threadIdx.x;
  const int lane = t & 63;
  const int wid  = t >> 6;
  const int wm   = wid & 1;
  const int wn   = wid >> 1;
  const int l31  = lane & 31;
  const int lh   = lane >> 5;

  const int b  = blockIdx.y;
  const int n0 = blockIdx.x * 128;
  const float* xb = x + (size_t)b * D * N + n0;

  float bestV[2] = {-3.402823466e38f, -3.402823466e38f};
  int   bestI[2] = {0, 0};

  for (int kt = 0; kt < K / 128; ++kt) {
    floatx16 acc[2][2];
    #pragma unroll
    for (int mt = 0; mt < 2; ++mt)
      #pragma unroll
      for (int nt = 0; nt < 2; ++nt)
        #pragma unroll
        for (int i = 0; i < 16; ++i) acc[mt][nt][i] = 0.f;

    for (int dt = 0; dt < D / 64; ++dt) {
      {
        const float* g0 = xb + (size_t)(dt * 64 + wid * 16 + lh) * N + l31 * 4;
        #pragma unroll
        for (int i = 0; i < 8; ++i) {
          async_ld16(g0 + (size_t)(i * 2) * N, &Xraw[(wid * 16 + i * 2) * 128]);
        }
      }
      {
        const float* eb = embed + (size_t)(kt * 128) * D + dt * 64;
        const int f4 = t & 15;
        const int cr = t >> 4;
        #pragma unroll
        for (int p = 0; p < 8; ++p) {
          int c = p * 16 + cr;
          const float4 v = *(const float4*)(eb + (size_t)c * D + f4 * 4);
          uint32_t h0, l0, h1, l1;
          split2(v.x, v.y, h0, l0);
          split2(v.z, v.w, h1, l1);
          int run = f4 >> 1, half = f4 & 1;
          int off = ((run ^ (c & 7)) * 8 + half * 4);
          *(uint2*)&Ehi[c * 64 + off] = make_uint2(h0, h1);
          *(uint2*)&Elo[c * 64 + off] = make_uint2(l0, l1);
        }
      }
      __syncthreads();

      #pragma unroll
      for (int ks = 0; ks < 4; ++ks) {
        short8 ahi[2], alo[2];
        #pragma unroll
        for (int mt = 0; mt < 2; ++mt) {
          int c = wm * 64 + mt * 32 + l31;
          int run = ks * 2 + lh;
          int off = (run ^ (c & 7)) * 8;
          ahi[mt] = *(const short8*)&Ehi[c * 64 + off];
          alo[mt] = *(const short8*)&Elo[c * 64 + off];
        }
        short8 bhi[2], blo[2];
        #pragma unroll
        for (int nt = 0; nt < 2; ++nt) {
          int n = wn * 64 + nt * 32 + l31;
          int kb = ks * 16 + lh * 8;
          float r0 = Xraw[(kb + 0) * 128 + n];
          float r1 = Xraw[(kb + 1) * 128 + n];
          float r2 = Xraw[(kb + 2) * 128 + n];
          float r3 = Xraw[(kb + 3) * 128 + n];
          float r4 = Xraw[(kb + 4) * 128 + n];
          float r5 = Xraw[(kb + 5) * 128 + n];
          float r6 = Xraw[(kb + 6) * 128 + n];
          float r7 = Xraw[(kb + 7) * 128 + n];
          union { short8 s; uint32_t u[4]; } Bh, Bl;
          split2(r0, r1, Bh.u[0], Bl.u[0]);
          split2(r2, r3, Bh.u[1], Bl.u[1]);
          split2(r4, r5, Bh.u[2], Bl.u[2]);
          split2(r6, r7, Bh.u[3], Bl.u[3]);
          bhi[nt] = Bh.s; blo[nt] = Bl.s;
        }
        #pragma unroll
        for (int mt = 0; mt < 2; ++mt)
          #pragma unroll
          for (int nt = 0; nt < 2; ++nt) {
            acc[mt][nt] = __builtin_amdgcn_mfma_f32_32x32x16_bf16(
                ahi[mt], bhi[nt], acc[mt][nt], 0, 0, 0);
            acc[mt][nt] = __builtin_amdgcn_mfma_f32_32x32x16_bf16(
                ahi[mt], blo[nt], acc[mt][nt], 0, 0, 0);
            acc[mt][nt] = __builtin_amdgcn_mfma_f32_32x32x16_bf16(
                alo[mt], bhi[nt], acc[mt][nt], 0, 0, 0);
          }
      }
      __syncthreads();
    } // dt

    #pragma unroll
    for (int mt = 0; mt < 2; ++mt) {
      #pragma unroll
      for (int r = 0; r < 16; ++r) {
        int row  = (r & 3) + 8 * (r >> 2) + 4 * lh;
        int code = kt * 128 + wm * 64 + mt * 32 + row;
        float ek = e2g[code];
        #pragma unroll
        for (int nt = 0; nt < 2; ++nt) {
          float s = 2.0f * acc[mt][nt][r] - ek;
          if (s > bestV[nt]) { bestV[nt] = s; bestI[nt] = code; }
        }
      }
    }
  } // kt

  __syncthreads();
  float* redV = Xraw;
  int*   redI = (int*)(Xraw + 512);
  int*   fIdx = (int*)(Xraw + 1024);

  #pragma unroll
  for (int nt = 0; nt < 2; ++nt) {
    int n = wn * 64 + nt * 32 + l31;
    int slot = lh + 2 * wm;
    redV[n * 4 + slot] = bestV[nt];
    redI[n * 4 + slot] = bestI[nt];
  }
  __syncthreads();
  if (t < 128) {
    float bv = redV[t * 4]; int bi = redI[t * 4];
    #pragma unroll
    for (int s = 1; s < 4; ++s) {
      float v = redV[t * 4 + s]; int ii = redI[t * 4 + s];
      if (v > bv || (v == bv && ii < bi)) { bv = v; bi = ii; }
    }
    fIdx[t] = bi;
    out[(size_t)B * D * N + (size_t)b * N + n0 + t] = (float)bi;
  }
  __syncthreads();

  {
    int n = t & 127;
    int code = fIdx[n];
    const float* erow = embed + (size_t)code * D;
    float* ob = out + (size_t)b * D * N + n0 + n;
    for (int d = (t >> 7); d < D; d += 2) {
      ob[(size_t)d * N] = erow[d];
    }
  }
}

extern "C" void kernel_launch(void* const* d_in, const int* in_sizes, int n_in,
                              void* d_out, int out_size, void* d_ws, size_t ws_size,
                              hipStream_t stream) {
  const float* x     = (const float*)d_in[0];
  const float* embed = (const float*)d_in[1];
  float* out = (float*)d_out;

  const size_t ES = (size_t)K * D;          // shorts per embed plane
  const size_t XS = (size_t)B * D * N;      // shorts per x plane
  const size_t need = 8192 + 2 * ES * 2 + 2 * XS * 2;  // 272,637,952 B

  float* e2 = (float*)d_ws;                 // 2048 floats (8 KB)

  if (ws_size >= need) {
    ushort* eh = (ushort*)((char*)d_ws + 8192);
    ushort* el = eh + ES;
    ushort* xhp = el + ES;
    ushort* xlp = xhp + XS;
    e2_kernel<<<dim3(K / 4), 256, 0, stream>>>(embed, e2);
    split_e<<<dim3(K / 16), 256, 0, stream>>>(embed, eh, el);
    split_x<<<dim3(N / 1024, D / 8, B), 256, 0, stream>>>(x, xhp, xlp);
    vq_mfma5<<<dim3(N / 256, B), 512, 0, stream>>>(xhp, xlp, eh, el, e2, embed, out);
  } else {
    e2_kernel<<<dim3(K / 4), 256, 0, stream>>>(embed, e2);
    vq_mfma<<<dim3(N / 128, B), 256, 0, stream>>>(x, embed, e2, out);
  }
}